// Round 10
// baseline (109.326 us; speedup 1.0000x reference)
//
#include <hip/hip_runtime.h>

// DeepQNetwork fused forward:  x(B,15) -> onehot(36) -> 128 -> 512 -> 40
// Transposed MFMA scheme (features = M, batch rows = N), v_mfma_f32_16x16x32_bf16.
// Ledger: R11/R12/R17 plateau 96.6-97.6 (2 waves/SIMD, RG=4). Falsified: ILP
// depth (R12), code size (R16), register-L1 (R14/R16), bank conflicts (R17
// neutral). Surviving theory: 2 phase-locked waves/SIMD -> ~60% no-issue
// cycles (R16 PMC: Mfma 20 / VALU 20 / HBM 7). R13 tested 4 waves/SIMD but
// launch_bounds(128,4) made the compiler squeeze to 64 VGPR and SPILL
// (WRITE_SIZE 31.7MB vs 21 = scratch): mechanism never actually tested.
// R18 = R13 shape with demotion fixed: __launch_bounds__(128) +
// amdgpu_waves_per_eu(3,4) -> VGPR budget 170 (>= ~130 working set), no
// spill, 3-4 desynced waves/SIMD. RG=2 (32 rows/wave), grid B/64 = 2048,
// LDS 9216B (6-8 blocks/CU). Rotation swizzle kept (R17: neutral cost,
// conflicts removed). ZERO barriers; all LDS wave-private.

typedef short bf16x8 __attribute__((ext_vector_type(8)));
typedef float f32x4 __attribute__((ext_vector_type(4)));
typedef unsigned int u32;

#define NW1F 8192              // 16 frags  (8 mt * 2 ks)
#define NW2F 65536             // 128 frags (32 mt * 4 ks)
#define NW4F 24576             // 48 frags  (3 mt * 16 ks)
#define PACK_TOTAL (NW1F + NW2F + NW4F)   // 98304 shorts = 192 KB of ws
#define PACK_THREADS (PACK_TOTAL / 8)     // one b128 store per thread

#define SROW 72                // LDS row stride in shorts (64 data + 8 pad)

__device__ __forceinline__ unsigned short f2bf(float f) {
  union { float f; unsigned u; } a; a.f = f;
  unsigned r = a.u + 0x7fffu + ((a.u >> 16) & 1u);
  return (unsigned short)(r >> 16);
}
// gfx950 packed convert, RNE: two f32 -> bf16x2 in one VALU op.
__device__ __forceinline__ u32 cvtpk(float lo, float hi) {
  u32 r;
  asm("v_cvt_pk_bf16_f32 %0, %1, %2" : "=v"(r) : "v"(lo), "v"(hi));
  return r;
}
// Rotation swizzle within one 64-short (8 x 16B-slot = 128B) region:
// physical short-offset for logical s (0..63) at LDS row `row`. Bijective per
// row; preserves 16B slot alignment and 8B sub-slot alignment.
__device__ __forceinline__ int swz(int row, int s) {
  return ((((s >> 3) + row) & 7) << 3) | (s & 7);
}

// Prepack W1^T (128x64, K-pad 36->64), W2^T (512x128), W4^T (48x512, M-pad 40->48)
// as A-fragment-linear bf16: frag*512 + lane*8 + j = A[m=mt*16+l16][k=ks*32+quad*8+j].
__global__ void pack_weights(const float* __restrict__ W1,
                             const float* __restrict__ W2,
                             const float* __restrict__ W4,
                             unsigned short* __restrict__ wf) {
  int t = blockIdx.x * 256 + threadIdx.x;
  if (t >= PACK_THREADS) return;
  int fid = t >> 6, lane = t & 63;
  int l16 = lane & 15, quad = lane >> 4;
  float vals[8];
  if (fid < 16) {                       // W1: fid = mt*2+ks
    int mt = fid >> 1, ks = fid & 1;
    int m = mt * 16 + l16, k0 = ks * 32 + quad * 8;
#pragma unroll
    for (int j = 0; j < 8; ++j) { int k = k0 + j; vals[j] = (k < 36) ? W1[k * 128 + m] : 0.f; }
  } else if (fid < 144) {               // W2: fid-16 = mt*4+ks
    int f = fid - 16, mt = f >> 2, ks = f & 3;
    int m = mt * 16 + l16, k0 = ks * 32 + quad * 8;
#pragma unroll
    for (int j = 0; j < 8; ++j) vals[j] = W2[(k0 + j) * 512 + m];
  } else {                              // W4: fid-144 = mt*16+ks
    int f = fid - 144, mt = f >> 4, ks = f & 15;
    int m = mt * 16 + l16, k0 = ks * 32 + quad * 8;
#pragma unroll
    for (int j = 0; j < 8; ++j) vals[j] = (m < 40) ? W4[(k0 + j) * 40 + m] : 0.f;
  }
  u32 p[4];
#pragma unroll
  for (int j = 0; j < 4; ++j) p[j] = cvtpk(vals[2 * j], vals[2 * j + 1]);
  *(bf16x8*)(wf + (size_t)t * 8) = *(bf16x8*)p;
}

// ---- stage-3 building blocks (mtl literal -> W parity folds) ----
#define MTL_STEP(chunk, mtl)                                                   \
  {                                                                            \
    f32x4 bias2 = *(const f32x4*)(b2 + (chunk) * 64 + (mtl) * 16 + quad * 4);  \
    int fb = (chunk) * 16 + (mtl) * 4 + 4;                                     \
    if (fb >= 128) fb = 0; /* harmless redundant load on last step */          \
    _Pragma("unroll")                                                          \
    for (int k = 0; k < 4; ++k)                                                \
      W[((mtl) + 1) & 1][k] = *(const bf16x8*)(w2p + (size_t)(fb + k) * 512);  \
    f32x4 acc2[2];                                                             \
    __builtin_amdgcn_s_setprio(1);                                             \
    _Pragma("unroll")                                                          \
    for (int rg = 0; rg < 2; ++rg)                                             \
      acc2[rg] = __builtin_amdgcn_mfma_f32_16x16x32_bf16(                      \
          W[(mtl) & 1][0], af1[rg][0], bias2, 0, 0, 0);                        \
    _Pragma("unroll")                                                          \
    for (int ks = 1; ks < 4; ++ks)                                             \
      _Pragma("unroll")                                                        \
      for (int rg = 0; rg < 2; ++rg)                                           \
        acc2[rg] = __builtin_amdgcn_mfma_f32_16x16x32_bf16(                    \
            W[(mtl) & 1][ks], af1[rg][ks], acc2[rg], 0, 0, 0);                 \
    __builtin_amdgcn_s_setprio(0);                                             \
    _Pragma("unroll")                                                          \
    for (int rg = 0; rg < 2; ++rg) {                                           \
      float v0 = fmaxf(acc2[rg][0], 0.f);                                      \
      float v1 = fmaxf(acc2[rg][1], 0.f);                                      \
      float v2 = fmaxf(acc2[rg][2], 0.f);                                      \
      float v3 = fmaxf(acc2[rg][3], 0.f);                                      \
      uint2 pk = {cvtpk(v0, v1), cvtpk(v2, v3)};                               \
      *(uint2*)(su + (rg * 16 + l16) * SROW                                    \
                + swz(rg * 16 + l16, (mtl) * 16 + quad * 4)) = pk;             \
    }                                                                          \
  }

#define H_READ(dst, ks3)                                                       \
  _Pragma("unroll")                                                            \
  for (int rg = 0; rg < 2; ++rg)                                               \
    dst[rg] = *(const bf16x8*)(su + (rg * 16 + l16) * SROW                     \
                               + swz(rg * 16 + l16, (ks3) * 32 + quad * 8));

#define W4_LOAD(dst, chunkprev, ks3)                                           \
  _Pragma("unroll")                                                            \
  for (int mt3 = 0; mt3 < 3; ++mt3)                                            \
    dst[mt3] = *(const bf16x8*)(                                               \
        w4f + (size_t)((mt3 * 16 + (chunkprev) * 2 + (ks3)) * 64 + lane) * 8);

#define L3_PART(w4q, hq)                                                       \
  __builtin_amdgcn_s_setprio(1);                                               \
  _Pragma("unroll")                                                            \
  for (int mt3 = 0; mt3 < 3; ++mt3)                                            \
    _Pragma("unroll")                                                          \
    for (int rg = 0; rg < 2; ++rg)                                             \
      accO[mt3][rg] = __builtin_amdgcn_mfma_f32_16x16x32_bf16(                 \
          w4q[mt3], hq[rg], accO[mt3][rg], 0, 0, 0);                           \
  __builtin_amdgcn_s_setprio(0);

// 128 threads = 2 waves; each wave privately owns 32 rows (2 N-groups of 16).
// All LDS traffic is wave-private (in-order per wave) -> NO barriers at all.
__global__ __launch_bounds__(128)
__attribute__((amdgpu_waves_per_eu(3, 4))) void dqn_fused(
    const float* __restrict__ x,
    const unsigned short* __restrict__ wf,
    const float* __restrict__ b1,
    const float* __restrict__ b2,
    const float* __restrict__ b4,
    float* __restrict__ out) {
  __shared__ __align__(16) unsigned short sBuf[2 * 32 * SROW];  // 9216 B

  const int tid  = threadIdx.x;
  const int lane = tid & 63;
  const int wave = tid >> 6;                     // 0 or 1
  const int quad = lane >> 4;
  const int l16  = lane & 15;
  const int row0 = blockIdx.x << 6;              // 64 rows per block
  const int lr0  = wave * 32;
  unsigned short* su = sBuf + wave * (32 * SROW);  // wave-private

  const unsigned short* w2f = wf + NW1F;
  const unsigned short* w4f = wf + NW1F + NW2F;
  const unsigned short* w2p = w2f + lane * 8;    // frag f lives at w2p + f*512

  // W2 pipeline prologue: frag-quad 0 -> parity buffer 0; latency overlaps
  // input staging + the whole L1 GEMM.
  bf16x8 W[2][4];
#pragma unroll
  for (int k = 0; k < 4; ++k) W[0][k] = *(const bf16x8*)(w2p + (size_t)k * 512);

  // ---- stage 1: one-hot input rows in LDS (bf16), K padded 36->64; lanes 0..31.
  // Every write goes through swz(row, s) — same rotation the readers use.
  if (lane < 32) {
    const float* xr = x + (size_t)(row0 + lr0 + lane) * 15;
    unsigned short* dst = su + lane * SROW;
    bf16x8 z = {0, 0, 0, 0, 0, 0, 0, 0};
#pragma unroll
    for (int c = 8; c < 64; c += 8) *(bf16x8*)(dst + swz(lane, c)) = z;  // slots 1..7
    u32 p[4];
#pragma unroll
    for (int i = 0; i < 4; ++i) p[i] = cvtpk(xr[2 * i], xr[2 * i + 1]);
    *(bf16x8*)(dst + swz(lane, 0)) = *(bf16x8*)p;            // cols 0..7
    *(u32*)(dst + swz(lane, 8)) = cvtpk(xr[8], xr[9]);       // cols 8..9
    dst[swz(lane, 10)] = f2bf(xr[10]);                       // col 10
    int hold = (int)xr[11]; hold = hold < 0 ? 0 : (hold > 3 ? 3 : hold);
    dst[swz(lane, 11 + hold)] = 0x3F80;                      // bf16 1.0
#pragma unroll
    for (int t = 0; t < 3; ++t) {
      int nx = (int)xr[12 + t] - 1; nx = nx < 0 ? 0 : (nx > 6 ? 6 : nx);
      dst[swz(lane, 15 + t * 7 + nx)] = 0x3F80;
    }
  }

  const f32x4 vzero = {0.f, 0.f, 0.f, 0.f};

  // ---- stage 2: h1^T = relu(W1^T @ inp^T + b1), two mt-halves; af1 to regs.
  bf16x8 ib[2][2];
#pragma unroll
  for (int rg = 0; rg < 2; ++rg)
#pragma unroll
    for (int ks = 0; ks < 2; ++ks)
      ib[rg][ks] = *(const bf16x8*)(su + (rg * 16 + l16) * SROW
                                    + swz(rg * 16 + l16, ks * 32 + quad * 8));

  bf16x8 af1[2][4];   // [rg][ks_out]: h1 B-frags, filled per half
#pragma unroll
  for (int half = 0; half < 2; ++half) {
    // hoist this half's 8 W1 frags before the MFMA bursts (latency overlap)
    bf16x8 wa[4][2];
#pragma unroll
    for (int mtl = 0; mtl < 4; ++mtl)
#pragma unroll
      for (int ks = 0; ks < 2; ++ks)
        wa[mtl][ks] = *(const bf16x8*)(
            wf + (size_t)(((half * 4 + mtl) * 2 + ks) * 64 + lane) * 8);

#pragma unroll
    for (int mtl = 0; mtl < 4; ++mtl) {
      f32x4 bias1 = *(const f32x4*)(b1 + (half * 4 + mtl) * 16 + quad * 4);
      f32x4 acc1[2];
      __builtin_amdgcn_s_setprio(1);
#pragma unroll
      for (int rg = 0; rg < 2; ++rg)
        acc1[rg] = __builtin_amdgcn_mfma_f32_16x16x32_bf16(wa[mtl][0], ib[rg][0], bias1, 0, 0, 0);
#pragma unroll
      for (int rg = 0; rg < 2; ++rg)
        acc1[rg] = __builtin_amdgcn_mfma_f32_16x16x32_bf16(wa[mtl][1], ib[rg][1], acc1[rg], 0, 0, 0);
      __builtin_amdgcn_s_setprio(0);
#pragma unroll
      for (int rg = 0; rg < 2; ++rg) {
        float v0 = fmaxf(acc1[rg][0], 0.f);
        float v1 = fmaxf(acc1[rg][1], 0.f);
        float v2 = fmaxf(acc1[rg][2], 0.f);
        float v3 = fmaxf(acc1[rg][3], 0.f);
        uint2 pk = {cvtpk(v0, v1), cvtpk(v2, v3)};
        *(uint2*)(su + (rg * 16 + l16) * SROW
                  + swz(rg * 16 + l16, mtl * 16 + quad * 4)) = pk;
      }
    }
#pragma unroll
    for (int rg = 0; rg < 2; ++rg)
#pragma unroll
      for (int ksl = 0; ksl < 2; ++ksl)
        af1[rg][half * 2 + ksl] =
            *(const bf16x8*)(su + (rg * 16 + l16) * SROW
                             + swz(rg * 16 + l16, ksl * 32 + quad * 8));
  }

  f32x4 accO[3][2];
#pragma unroll
  for (int mt = 0; mt < 3; ++mt)
#pragma unroll
    for (int rg = 0; rg < 2; ++rg) accO[mt][rg] = vzero;

  // ---- stage 3: single h2 buffer; per-wave in-order DS gives RAW/WAR safety:
  // chunk c's H_READs of chunk c-1's h2 are ISSUED before chunk c's writes.
  MTL_STEP(0, 0)
  MTL_STEP(0, 1)
  MTL_STEP(0, 2)
  MTL_STEP(0, 3)
  for (int chunk = 1; chunk < 8; ++chunk) {
    bf16x8 h0[2];
    H_READ(h0, 0)                       // prev chunk cols 0..31, before MTL0/1 overwrite
    MTL_STEP(chunk, 0)
    MTL_STEP(chunk, 1)
    bf16x8 w4a[3];
    W4_LOAD(w4a, chunk - 1, 0)
    L3_PART(w4a, h0)
    bf16x8 h1v[2];
    H_READ(h1v, 1)                      // prev chunk cols 32..63, before MTL2/3 overwrite
    MTL_STEP(chunk, 2)
    MTL_STEP(chunk, 3)
    bf16x8 w4b[3];
    W4_LOAD(w4b, chunk - 1, 1)
    L3_PART(w4b, h1v)
  }
  {
    // pipeline tail: L3 partial of chunk 7 (reads AFTER its writes in order)
    bf16x8 h0[2];
    H_READ(h0, 0)
    bf16x8 h1v[2];
    H_READ(h1v, 1)
    bf16x8 w4a[3];
    W4_LOAD(w4a, 7, 0)
    L3_PART(w4a, h0)
    bf16x8 w4b[3];
    W4_LOAD(w4b, 7, 1)
    L3_PART(w4b, h1v)
  }

  // ---- epilogue: +b4, float4 stores (lane holds 4 consecutive out-cols) ----
#pragma unroll
  for (int mt3 = 0; mt3 < 3; ++mt3) {
    int colbase = mt3 * 16 + quad * 4;
    if (colbase < 40) {                      // drops pad cols 40..47
      f32x4 bias = *(const f32x4*)(b4 + colbase);
#pragma unroll
      for (int rg = 0; rg < 2; ++rg) {
        f32x4 v = accO[mt3][rg] + bias;
        size_t row = (size_t)(row0 + lr0 + rg * 16 + l16);
        *(f32x4*)(out + row * 40 + colbase) = v;
      }
    }
  }
}

extern "C" void kernel_launch(void* const* d_in, const int* in_sizes, int n_in,
                              void* d_out, int out_size, void* d_ws, size_t ws_size,
                              hipStream_t stream) {
  const float* x  = (const float*)d_in[0];
  const float* W1 = (const float*)d_in[1];
  const float* b1 = (const float*)d_in[2];
  const float* W2 = (const float*)d_in[3];
  const float* b2 = (const float*)d_in[4];
  const float* W4 = (const float*)d_in[5];
  const float* b4 = (const float*)d_in[6];
  float* out = (float*)d_out;
  unsigned short* wf = (unsigned short*)d_ws;   // 192 KB of ws

  int B = in_sizes[0] / 15;

  hipLaunchKernelGGL(pack_weights, dim3((PACK_THREADS + 255) / 256), dim3(256), 0, stream,
                     W1, W2, W4, wf);
  hipLaunchKernelGGL(dqn_fused, dim3(B / 64), dim3(128), 0, stream,
                     x, wf, b1, b2, b4, out);
}

// Round 11
// 95.761 us; speedup vs baseline: 1.1417x; 1.1417x over previous
//
#include <hip/hip_runtime.h>

// DeepQNetwork fused forward:  x(B,15) -> onehot(36) -> 128 -> 512 -> 40
// Transposed MFMA scheme (features = M, batch rows = N), v_mfma_f32_16x16x32_bf16:
//   A frag (weights, prepacked fragment-linear in ws): lane = A[m=l16][k=quad*8+j]
//   B frag (activations): lane = act[row=l16][feat=quad*8+j] -> ds_read_b128
//   C/D: lane reg r = D[feat=quad*4+r][row=l16] -> pack 4 feats -> one ds_write_b64
// SESSION LEDGER (best = R11, 96.6us): falsified theories: ILP depth (R12
// 2-deep prefetch, neutral), TLP (R13/R18: all RG=2 variants stuck at ~44us
// fused at ANY occupancy; RG=4 = 768 MFMA/wave is the right compute/load
// ratio), register-L1 (R14/R16 regressed: serial uncoalesced head), code size
// (R16), LDS bank conflicts (R17 swizzle neutral at RG=4, HARMFUL at RG=2).
// R19 = exact R11 restore + one fix: stage-2 bias1 loads issued BEFORE the wa
// loads, so the acc-init waits vmcnt(8) instead of vmcnt(0) (no full VMEM
// queue drain, 2x per kernel). Chunk-0 bias2 likewise ordered before W4/W2
// prefetches. No swizzle. ZERO barriers; all LDS wave-private (per-wave
// in-order DS). 2-wave blocks (64 rows/wave), grid 1024, LDS 34816B.

typedef short bf16x8 __attribute__((ext_vector_type(8)));
typedef float f32x4 __attribute__((ext_vector_type(4)));
typedef unsigned int u32;

#define NW1F 8192              // 16 frags  (8 mt * 2 ks)
#define NW2F 65536             // 128 frags (32 mt * 4 ks)
#define NW4F 24576             // 48 frags  (3 mt * 16 ks)
#define PACK_TOTAL (NW1F + NW2F + NW4F)   // 98304 shorts = 192 KB of ws
#define PACK_THREADS (PACK_TOTAL / 8)     // one b128 store per thread

#define SROW 136               // LDS row stride in shorts (h1 0..63 | pad | h2b 72..135)

__device__ __forceinline__ unsigned short f2bf(float f) {
  union { float f; unsigned u; } a; a.f = f;
  unsigned r = a.u + 0x7fffu + ((a.u >> 16) & 1u);
  return (unsigned short)(r >> 16);
}
// gfx950 packed convert, RNE: two f32 -> bf16x2 in one VALU op.
__device__ __forceinline__ u32 cvtpk(float lo, float hi) {
  u32 r;
  asm("v_cvt_pk_bf16_f32 %0, %1, %2" : "=v"(r) : "v"(lo), "v"(hi));
  return r;
}

// Prepack W1^T (128x64, K-pad 36->64), W2^T (512x128), W4^T (48x512, M-pad 40->48)
// as A-fragment-linear bf16: frag*512 + lane*8 + j = A[m=mt*16+l16][k=ks*32+quad*8+j].
__global__ void pack_weights(const float* __restrict__ W1,
                             const float* __restrict__ W2,
                             const float* __restrict__ W4,
                             unsigned short* __restrict__ wf) {
  int t = blockIdx.x * 256 + threadIdx.x;
  if (t >= PACK_THREADS) return;
  int fid = t >> 6, lane = t & 63;
  int l16 = lane & 15, quad = lane >> 4;
  float vals[8];
  if (fid < 16) {                       // W1: fid = mt*2+ks
    int mt = fid >> 1, ks = fid & 1;
    int m = mt * 16 + l16, k0 = ks * 32 + quad * 8;
#pragma unroll
    for (int j = 0; j < 8; ++j) { int k = k0 + j; vals[j] = (k < 36) ? W1[k * 128 + m] : 0.f; }
  } else if (fid < 144) {               // W2: fid-16 = mt*4+ks
    int f = fid - 16, mt = f >> 2, ks = f & 3;
    int m = mt * 16 + l16, k0 = ks * 32 + quad * 8;
#pragma unroll
    for (int j = 0; j < 8; ++j) vals[j] = W2[(k0 + j) * 512 + m];
  } else {                              // W4: fid-144 = mt*16+ks
    int f = fid - 144, mt = f >> 4, ks = f & 15;
    int m = mt * 16 + l16, k0 = ks * 32 + quad * 8;
#pragma unroll
    for (int j = 0; j < 8; ++j) vals[j] = (m < 40) ? W4[(k0 + j) * 40 + m] : 0.f;
  }
  u32 p[4];
#pragma unroll
  for (int j = 0; j < 4; ++j) p[j] = cvtpk(vals[2 * j], vals[2 * j + 1]);
  *(bf16x8*)(wf + (size_t)t * 8) = *(bf16x8*)p;
}

// ---- stage-3 building-block macros (literal args only -> all reg indices fold) ----
// One W2 mtl-step of `chunk`: prefetch next W frag-quad, 16 MFMAs, relu+pack to
// h2 buffer at column offset hb.
#define MTL_STEP(chunk, mtl, hb)                                               \
  {                                                                            \
    int fb = (chunk) * 16 + (mtl) * 4 + 4;                                     \
    if (fb >= 128) fb = 0; /* harmless redundant load on last step */          \
    _Pragma("unroll")                                                          \
    for (int k = 0; k < 4; ++k)                                                \
      W[((mtl) + 1) & 1][k] = *(const bf16x8*)(w2p + (size_t)(fb + k) * 512);  \
    f32x4 acc2[4];                                                             \
    _Pragma("unroll")                                                          \
    for (int rg = 0; rg < 4; ++rg) acc2[rg] = bias2[mtl];                      \
    __builtin_amdgcn_s_setprio(1);                                             \
    _Pragma("unroll")                                                          \
    for (int ks = 0; ks < 4; ++ks)                                             \
      _Pragma("unroll")                                                        \
      for (int rg = 0; rg < 4; ++rg)                                           \
        acc2[rg] = __builtin_amdgcn_mfma_f32_16x16x32_bf16(                    \
            W[(mtl) & 1][ks], af1[rg][ks], acc2[rg], 0, 0, 0);                 \
    __builtin_amdgcn_s_setprio(0);                                             \
    _Pragma("unroll")                                                          \
    for (int rg = 0; rg < 4; ++rg) {                                           \
      float v0 = fmaxf(acc2[rg][0], 0.f);                                      \
      float v1 = fmaxf(acc2[rg][1], 0.f);                                      \
      float v2 = fmaxf(acc2[rg][2], 0.f);                                      \
      float v3 = fmaxf(acc2[rg][3], 0.f);                                      \
      uint2 pk = {cvtpk(v0, v1), cvtpk(v2, v3)};                               \
      *(uint2*)(su + (rg * 16 + l16) * SROW + (hb) + (mtl) * 16 + quad * 4) = pk; \
    }                                                                          \
  }

#define H_READ(dst, hbp, ks3)                                                  \
  _Pragma("unroll")                                                            \
  for (int rg = 0; rg < 4; ++rg)                                               \
    dst[rg] = *(const bf16x8*)(su + (rg * 16 + l16) * SROW + (hbp) + (ks3) * 32 + quad * 8);

#define W4_LOAD(dst, chunkprev, ks3)                                           \
  _Pragma("unroll")                                                            \
  for (int mt3 = 0; mt3 < 3; ++mt3)                                            \
    dst[mt3] = *(const bf16x8*)(                                               \
        w4f + (size_t)((mt3 * 16 + (chunkprev) * 2 + (ks3)) * 64 + lane) * 8);

#define L3_PART(w4q, hq)                                                       \
  __builtin_amdgcn_s_setprio(1);                                               \
  _Pragma("unroll")                                                            \
  for (int mt3 = 0; mt3 < 3; ++mt3)                                            \
    _Pragma("unroll")                                                          \
    for (int rg = 0; rg < 4; ++rg)                                             \
      accO[mt3][rg] = __builtin_amdgcn_mfma_f32_16x16x32_bf16(                 \
          w4q[mt3], hq[rg], accO[mt3][rg], 0, 0, 0);                           \
  __builtin_amdgcn_s_setprio(0);

// 128 threads = 2 waves; each wave privately owns 64 rows (4 N-groups of 16).
// All LDS traffic is wave-private (DS ops complete in order per wave) -> the
// kernel contains NO __syncthreads / s_barrier at all.
__global__ __launch_bounds__(128, 2) void dqn_fused(
    const float* __restrict__ x,
    const unsigned short* __restrict__ wf,
    const float* __restrict__ b1,
    const float* __restrict__ b2,
    const float* __restrict__ b4,
    float* __restrict__ out) {
  __shared__ __align__(16) unsigned short sBuf[2 * 64 * SROW];  // 34816 B -> 4 blocks/CU

  const int tid  = threadIdx.x;
  const int lane = tid & 63;
  const int wave = tid >> 6;                     // 0 or 1
  const int quad = lane >> 4;
  const int l16  = lane & 15;
  const int row0 = blockIdx.x << 7;              // 128 rows per block
  const int lr0  = wave * 64;
  unsigned short* su = sBuf + wave * (64 * SROW);  // wave-private

  const unsigned short* w2f = wf + NW1F;
  const unsigned short* w4f = wf + NW1F + NW2F;
  const unsigned short* w2p = w2f + lane * 8;    // frag f lives at w2p + f*512

  // software-pipeline prologue: W2 frag-quad 0 into parity buffer 0; its
  // latency overlaps input staging + the whole L1 GEMM.
  bf16x8 W[2][4];
#pragma unroll
  for (int k = 0; k < 4; ++k) W[0][k] = *(const bf16x8*)(w2p + (size_t)k * 512);

  // ---- stage 1: one-hot input rows in LDS (bf16), K padded 36->64; 1 row/lane ----
  {
    const float* xr = x + (size_t)(row0 + lr0 + lane) * 15;
    unsigned short* dst = su + lane * SROW;
    bf16x8 z = {0, 0, 0, 0, 0, 0, 0, 0};
#pragma unroll
    for (int c = 8; c < 64; c += 8) *(bf16x8*)(dst + c) = z;   // zero cols 8..63
    u32 p[4];
#pragma unroll
    for (int i = 0; i < 4; ++i) p[i] = cvtpk(xr[2 * i], xr[2 * i + 1]);
    *(bf16x8*)dst = *(bf16x8*)p;                 // keep cols 0..7
    *(u32*)(dst + 8) = cvtpk(xr[8], xr[9]);      // keep cols 8..9
    dst[10] = f2bf(xr[10]);                      // keep col 10
    int hold = (int)xr[11]; hold = hold < 0 ? 0 : (hold > 3 ? 3 : hold);
    dst[11 + hold] = 0x3F80;                     // bf16 1.0
#pragma unroll
    for (int t = 0; t < 3; ++t) {
      int nx = (int)xr[12 + t] - 1; nx = nx < 0 ? 0 : (nx > 6 ? 6 : nx);
      dst[15 + t * 7 + nx] = 0x3F80;
    }
  }

  const f32x4 vzero = {0.f, 0.f, 0.f, 0.f};

  // ---- stage 2: h1^T = relu(W1^T @ inp^T + b1), two mt-halves; af1 frags to regs.
  bf16x8 ib[4][2];
#pragma unroll
  for (int rg = 0; rg < 4; ++rg)
#pragma unroll
    for (int ks = 0; ks < 2; ++ks)
      ib[rg][ks] = *(const bf16x8*)(su + (rg * 16 + l16) * SROW + ks * 32 + quad * 8);

  bf16x8 af1[4][4];   // [rg][ks_out]: h1 B-frags, filled per half
#pragma unroll
  for (int half = 0; half < 2; ++half) {
    // bias1 loads FIRST, then wa loads: acc-init then waits vmcnt(8) (wa in
    // flight) instead of vmcnt(0) — no full VMEM queue drain before the burst.
    f32x4 bias1[4];
#pragma unroll
    for (int mtl = 0; mtl < 4; ++mtl)
      bias1[mtl] = *(const f32x4*)(b1 + (half * 4 + mtl) * 16 + quad * 4);
    bf16x8 wa[4][2];
#pragma unroll
    for (int mtl = 0; mtl < 4; ++mtl)
#pragma unroll
      for (int ks = 0; ks < 2; ++ks)
        wa[mtl][ks] = *(const bf16x8*)(
            wf + (size_t)(((half * 4 + mtl) * 2 + ks) * 64 + lane) * 8);

    f32x4 acc1[4][4];   // [mtl][rg]
#pragma unroll
    for (int mtl = 0; mtl < 4; ++mtl)
#pragma unroll
      for (int rg = 0; rg < 4; ++rg) acc1[mtl][rg] = bias1[mtl];

    __builtin_amdgcn_s_setprio(1);
#pragma unroll
    for (int mtl = 0; mtl < 4; ++mtl)
#pragma unroll
      for (int ks = 0; ks < 2; ++ks)
#pragma unroll
        for (int rg = 0; rg < 4; ++rg)
          acc1[mtl][rg] = __builtin_amdgcn_mfma_f32_16x16x32_bf16(wa[mtl][ks], ib[rg][ks], acc1[mtl][rg], 0, 0, 0);
    __builtin_amdgcn_s_setprio(0);

#pragma unroll
    for (int mtl = 0; mtl < 4; ++mtl) {
#pragma unroll
      for (int rg = 0; rg < 4; ++rg) {
        float v0 = fmaxf(acc1[mtl][rg][0], 0.f);
        float v1 = fmaxf(acc1[mtl][rg][1], 0.f);
        float v2 = fmaxf(acc1[mtl][rg][2], 0.f);
        float v3 = fmaxf(acc1[mtl][rg][3], 0.f);
        uint2 pk = {cvtpk(v0, v1), cvtpk(v2, v3)};
        *(uint2*)(su + (rg * 16 + l16) * SROW + mtl * 16 + quad * 4) = pk;
      }
    }
#pragma unroll
    for (int rg = 0; rg < 4; ++rg)
#pragma unroll
      for (int ksl = 0; ksl < 2; ++ksl)
        af1[rg][half * 2 + ksl] =
            *(const bf16x8*)(su + (rg * 16 + l16) * SROW + ksl * 32 + quad * 8);
  }

  f32x4 accO[3][4];
#pragma unroll
  for (int mt = 0; mt < 3; ++mt)
#pragma unroll
    for (int rg = 0; rg < 4; ++rg) accO[mt][rg] = vzero;

  // ---- stage 3: chunk-level software pipeline, no barriers ----
  // chunk c's W2 bursts fill h2 buffer (c&1); chunk c-1's L3 partial is
  // interleaved into c's mtl loop reading buffer ((c-1)&1).
  {
    // chunk 0: bias2 loads first (vmcnt-distance from their use), then fill buf0
    f32x4 bias2[4];
#pragma unroll
    for (int mtl = 0; mtl < 4; ++mtl)
      bias2[mtl] = *(const f32x4*)(b2 + mtl * 16 + quad * 4);
    MTL_STEP(0, 0, 0)
    MTL_STEP(0, 1, 0)
    MTL_STEP(0, 2, 0)
    MTL_STEP(0, 3, 0)
  }
  for (int chunk = 1; chunk < 8; ++chunk) {
    const int hb  = (chunk & 1) * 72;   // current h2 buffer column offset
    const int hbp = 72 - hb;            // previous chunk's buffer
    f32x4 bias2[4];
#pragma unroll
    for (int mtl = 0; mtl < 4; ++mtl)
      bias2[mtl] = *(const f32x4*)(b2 + chunk * 64 + mtl * 16 + quad * 4);

    bf16x8 w4a[3];
    W4_LOAD(w4a, chunk - 1, 0)          // global loads ~2 mtl-steps ahead of use
    MTL_STEP(chunk, 0, hb)
    bf16x8 h0[4];
    H_READ(h0, hbp, 0)                  // ds_reads one mtl-step ahead of use
    MTL_STEP(chunk, 1, hb)
    L3_PART(w4a, h0)
    bf16x8 w4b[3];
    W4_LOAD(w4b, chunk - 1, 1)
    MTL_STEP(chunk, 2, hb)
    bf16x8 h1v[4];
    H_READ(h1v, hbp, 1)
    MTL_STEP(chunk, 3, hb)
    L3_PART(w4b, h1v)
  }
  {
    // pipeline tail: L3 partial of chunk 7 (buffer offset 72)
    bf16x8 w4a[3];
    W4_LOAD(w4a, 7, 0)
    bf16x8 h0[4];
    H_READ(h0, 72, 0)
    L3_PART(w4a, h0)
    bf16x8 w4b[3];
    W4_LOAD(w4b, 7, 1)
    bf16x8 h1v[4];
    H_READ(h1v, 72, 1)
    L3_PART(w4b, h1v)
  }

  // ---- epilogue: +b4, float4 stores (lane holds 4 consecutive out-cols) ----
#pragma unroll
  for (int mt3 = 0; mt3 < 3; ++mt3) {
    int colbase = mt3 * 16 + quad * 4;
    if (colbase < 40) {                      // drops pad cols 40..47 (b4 OOB-safe)
      f32x4 bias = *(const f32x4*)(b4 + colbase);
#pragma unroll
      for (int rg = 0; rg < 4; ++rg) {
        f32x4 v = accO[mt3][rg] + bias;
        size_t row = (size_t)(row0 + lr0 + rg * 16 + l16);
        *(f32x4*)(out + row * 40 + colbase) = v;
      }
    }
  }
}

extern "C" void kernel_launch(void* const* d_in, const int* in_sizes, int n_in,
                              void* d_out, int out_size, void* d_ws, size_t ws_size,
                              hipStream_t stream) {
  const float* x  = (const float*)d_in[0];
  const float* W1 = (const float*)d_in[1];
  const float* b1 = (const float*)d_in[2];
  const float* W2 = (const float*)d_in[3];
  const float* b2 = (const float*)d_in[4];
  const float* W4 = (const float*)d_in[5];
  const float* b4 = (const float*)d_in[6];
  float* out = (float*)d_out;
  unsigned short* wf = (unsigned short*)d_ws;   // 192 KB of ws

  int B = in_sizes[0] / 15;

  hipLaunchKernelGGL(pack_weights, dim3((PACK_THREADS + 255) / 256), dim3(256), 0, stream,
                     W1, W2, W4, wf);
  hipLaunchKernelGGL(dqn_fused, dim3(B / 128), dim3(128), 0, stream,
                     x, wf, b1, b2, b4, out);
}